// Round 8
// baseline (215.101 us; speedup 1.0000x reference)
//
#include <hip/hip_runtime.h>
#include <hip/hip_bf16.h>
#include <stdint.h>

// B=4, S=1024, D=1024, H=16, M=64, DH=64
#define SB 1024
#define DD 1024
#define NH 16
#define MM 64
#define DHD 64

typedef __attribute__((ext_vector_type(8))) short s16x8;
typedef __attribute__((ext_vector_type(4))) float f32x4;

__device__ __forceinline__ unsigned short f2bf(float f) {
    union { float f; unsigned int u; } v; v.f = f;
    unsigned int u = v.u;
    u += 0x7FFFu + ((u >> 16) & 1u);
    return (unsigned short)(u >> 16);
}

__device__ __forceinline__ void gload_lds16(const unsigned short* g, unsigned short* l) {
    __builtin_amdgcn_global_load_lds(
        (const __attribute__((address_space(1))) unsigned int*)g,
        (__attribute__((address_space(3))) unsigned int*)l, 16, 0, 0);
}

// ---------------------------------------------------------------------------
// Merged: q/k/v f32->bf16 (blocks 0..6143) + W transpose/convert (6144..10239).
// ---------------------------------------------------------------------------
__global__ __launch_bounds__(256) void cvtw_kernel(const float* q, const float* k, const float* v,
                                                   unsigned short* qb, unsigned short* kb,
                                                   unsigned short* vb,
                                                   const float* W0, const float* W1,
                                                   const float* W2, const float* W3,
                                                   unsigned short* Wt) {
    const int bid = blockIdx.x, tid = threadIdx.x;
    __shared__ float tile[32][33];
    if (bid < 6144) {
        const int z = bid >> 11;
        const float* src = (z == 0) ? q : (z == 1) ? k : v;
        unsigned short* dst = (z == 0) ? qb : (z == 1) ? kb : vb;
        const size_t base = ((size_t)(bid & 2047) * 256 + tid) * 8;
        f32x4 a = *(const f32x4*)(src + base);
        f32x4 b2 = *(const f32x4*)(src + base + 4);
        s16x8 t;
        t[0] = (short)f2bf(a[0]);  t[1] = (short)f2bf(a[1]);
        t[2] = (short)f2bf(a[2]);  t[3] = (short)f2bf(a[3]);
        t[4] = (short)f2bf(b2[0]); t[5] = (short)f2bf(b2[1]);
        t[6] = (short)f2bf(b2[2]); t[7] = (short)f2bf(b2[3]);
        *(s16x8*)(dst + base) = t;
    } else {
        const int wt = bid - 6144;
        const int z = wt >> 10, rem = wt & 1023;
        const int x0 = (rem & 31) * 32, y0 = (rem >> 5) * 32;
        const float* W = (z == 0) ? W0 : (z == 1) ? W1 : (z == 2) ? W2 : W3;
        unsigned short* Wo_ = Wt + (size_t)z * DD * DD;
        const int tx = tid & 31, ty = tid >> 5;
#pragma unroll
        for (int j = 0; j < 4; ++j)
            tile[ty + 8 * j][tx] = W[(size_t)(y0 + ty + 8 * j) * DD + x0 + tx];
        __syncthreads();
#pragma unroll
        for (int j = 0; j < 4; ++j)
            Wo_[(size_t)(x0 + ty + 8 * j) * DD + y0 + tx] = f2bf(tile[tx][ty + 8 * j]);
    }
}

// ---------------------------------------------------------------------------
// GEMM body: C[128x128 tile at (m0b,n0b)] = A @ Bt^T, bf16 MFMA, BK=64,
// 512 threads, gload_lds(16) + XOR-swizzled source, double-buffered.
// LDS tile passed in by the kernel (single allocation across instantiations).
// OMODE 0: head-split bf16; 1: v-transposed bf16; 2: f32 flat.
// ---------------------------------------------------------------------------
typedef unsigned short LdsTile[2][2][128][64];

template <int OMODE>
__device__ __forceinline__ void gemm_body(const unsigned short* A, const unsigned short* Bt,
                                          void* outp, int m0b, int n0b, LdsTile& lds) {
    const int tid = threadIdx.x, l = tid & 63, w = tid >> 6;
    const int l15 = l & 15, lq = l >> 4;
    const int wm = (w >> 1) * 32, wn = (w & 1) * 64;
    const int ric = l >> 3;
    const int gsrc = (l & 7) ^ (ric & 7);

    f32x4 acc[2][4];
#pragma unroll
    for (int i = 0; i < 2; ++i)
#pragma unroll
        for (int j = 0; j < 4; ++j) acc[i][j] = (f32x4){0.f, 0.f, 0.f, 0.f};

    auto STAGE = [&](int bb, int kt) {
        const int k0 = kt * 64;
#pragma unroll
        for (int j = 0; j < 2; ++j) {
            const int chunk = w * 2 + j;
            const int r = chunk * 8 + ric;
            gload_lds16(A + (size_t)(m0b + r) * DD + k0 + gsrc * 8, &lds[bb][0][chunk * 8][0]);
            gload_lds16(Bt + (size_t)(n0b + r) * DD + k0 + gsrc * 8, &lds[bb][1][chunk * 8][0]);
        }
    };

    STAGE(0, 0);
    __syncthreads();
    int cur = 0;
    for (int kt = 0; kt < 16; ++kt) {
        if (kt < 15) STAGE(cur ^ 1, kt + 1);
#pragma unroll
        for (int kt2 = 0; kt2 < 2; ++kt2) {
            s16x8 af[2], bf[4];
#pragma unroll
            for (int mi = 0; mi < 2; ++mi) {
                const int R = wm + mi * 16 + l15;
                af[mi] = *(const s16x8*)(&lds[cur][0][R][((kt2 * 4 + lq) ^ (R & 7)) * 8]);
            }
#pragma unroll
            for (int ni = 0; ni < 4; ++ni) {
                const int R = wn + ni * 16 + l15;
                bf[ni] = *(const s16x8*)(&lds[cur][1][R][((kt2 * 4 + lq) ^ (R & 7)) * 8]);
            }
#pragma unroll
            for (int mi = 0; mi < 2; ++mi)
#pragma unroll
                for (int ni = 0; ni < 4; ++ni)
                    acc[mi][ni] = __builtin_amdgcn_mfma_f32_16x16x32_bf16(af[mi], bf[ni],
                                                                          acc[mi][ni], 0, 0, 0);
        }
        __syncthreads();
        cur ^= 1;
    }

#pragma unroll
    for (int mi = 0; mi < 2; ++mi)
#pragma unroll
        for (int ni = 0; ni < 4; ++ni)
#pragma unroll
            for (int i = 0; i < 4; ++i) {
                const int r = m0b + wm + mi * 16 + lq * 4 + i;
                const int c = n0b + wn + ni * 16 + l15;
                const float vv = acc[mi][ni][i];
                if (OMODE == 2) {
                    ((float*)outp)[(size_t)r * DD + c] = vv;
                } else {
                    const int b = r >> 10, s = r & 1023;
                    const int hh = c >> 6, dh = c & 63;
                    if (OMODE == 0)
                        ((unsigned short*)outp)[((size_t)((b * NH + hh) * SB + s)) * DHD + dh] = f2bf(vv);
                    else
                        ((unsigned short*)outp)[((size_t)((b * NH + hh) * DHD + dh)) * SB + s] = f2bf(vv);
                }
            }
}

// XCD-aware decode: 256 blocks/tensor; 4 consecutive A-panels + whole B per XCD
// -> per-XCD L2 working set ~3MB (fits 4MB).
__device__ __forceinline__ void xcd_decode(int i, int& m0b, int& n0b) {
    const int xcd = i & 7, idx = i >> 3;
    m0b = (xcd * 4 + (idx >> 3)) * 128;
    n0b = (idx & 7) * 128;
}

// Fused QKV projections: grid 768 = 3 tensors x 256 tiles.
__global__ __launch_bounds__(512, 4) void gemm_qkv_kernel(const unsigned short* qb,
                                                          const unsigned short* kb,
                                                          const unsigned short* vb,
                                                          const unsigned short* Wt,
                                                          unsigned short* qhp, unsigned short* khp,
                                                          unsigned short* vht) {
    __shared__ LdsTile lds;
    const int wg = blockIdx.x;
    const int t = wg >> 8, i = wg & 255;
    int m0b, n0b;
    xcd_decode(i, m0b, n0b);
    const unsigned short* Bt = Wt + (size_t)t * DD * DD;
    if (t == 0)      gemm_body<0>(qb, Bt, qhp, m0b, n0b, lds);
    else if (t == 1) gemm_body<0>(kb, Bt, khp, m0b, n0b, lds);
    else             gemm_body<1>(vb, Bt, vht, m0b, n0b, lds);
}

// Output projection: grid 256.
__global__ __launch_bounds__(512, 4) void gemm_o_kernel(const unsigned short* aout,
                                                        const unsigned short* WtO, float* out) {
    __shared__ LdsTile lds;
    int m0b, n0b;
    xcd_decode(blockIdx.x, m0b, n0b);
    gemm_body<2>(aout, WtO, out, m0b, n0b, lds);
}

// ---------------------------------------------------------------------------
// Merged uk+gram. Blocks 0..63: U[bh] = vht[bh] @ kvm[b]  (bf16 [dh][m]).
// Blocks 64..67: cscale[b] = alpha / (sqrt(alpha^2 * sum(Gq o Gk)) + 1e-5).
// ---------------------------------------------------------------------------
__global__ __launch_bounds__(256) void ukgram_kernel(const unsigned short* vht, const float* qm,
                                                     const float* kvm, const float* alpha_p,
                                                     unsigned short* U, float* cscale) {
    __shared__ char lds_raw[81952];
    float (*part)[64][64] = (float (*)[64][64])lds_raw;          // 64KB
    float (*gq)[64] = (float (*)[64])(lds_raw + 65536);          // 16KB
    float* red = (float*)(lds_raw + 81920);                      // 16B+

    const int bid = blockIdx.x;
    const int tid = threadIdx.x, l = tid & 63, w = tid >> 6;
    const int l15 = l & 15, lq = l >> 4;

    if (bid < 64) {
        const int bh = bid, b = bh >> 4;
        f32x4 acc[4][4];
#pragma unroll
        for (int i = 0; i < 4; ++i)
#pragma unroll
            for (int j = 0; j < 4; ++j) acc[i][j] = (f32x4){0.f, 0.f, 0.f, 0.f};
        for (int kt2 = 0; kt2 < 8; ++kt2) {
            const int sbase = w * 256 + kt2 * 32 + 8 * lq;
            s16x8 av[4], bk[4];
#pragma unroll
            for (int t = 0; t < 4; ++t)
                av[t] = *(const s16x8*)(vht + ((size_t)bh * DHD + t * 16 + l15) * SB + sbase);
#pragma unroll
            for (int t = 0; t < 4; ++t) {
                s16x8 tmp;
#pragma unroll
                for (int j = 0; j < 8; ++j)
                    tmp[j] = (short)f2bf(kvm[((size_t)b * SB + sbase + j) * MM + t * 16 + l15]);
                bk[t] = tmp;
            }
#pragma unroll
            for (int at = 0; at < 4; ++at)
#pragma unroll
                for (int bt = 0; bt < 4; ++bt)
                    acc[at][bt] = __builtin_amdgcn_mfma_f32_16x16x32_bf16(av[at], bk[bt],
                                                                          acc[at][bt], 0, 0, 0);
        }
#pragma unroll
        for (int at = 0; at < 4; ++at)
#pragma unroll
            for (int bt = 0; bt < 4; ++bt)
#pragma unroll
                for (int i = 0; i < 4; ++i)
                    part[w][at * 16 + lq * 4 + i][bt * 16 + l15] = acc[at][bt][i];
        __syncthreads();
        for (int e = tid * 16; e < tid * 16 + 16; ++e) {
            const int r = e >> 6, c = e & 63;
            U[(size_t)bh * 4096 + e] =
                f2bf(part[0][r][c] + part[1][r][c] + part[2][r][c] + part[3][r][c]);
        }
    } else {
        const int b = bid - 64;
        f32x4 acc[4][4];
        // phase 1: Gq
#pragma unroll
        for (int i = 0; i < 4; ++i)
#pragma unroll
            for (int j = 0; j < 4; ++j) acc[i][j] = (f32x4){0.f, 0.f, 0.f, 0.f};
        for (int kt2 = 0; kt2 < 8; ++kt2) {
            const int sbase = w * 256 + kt2 * 32 + 8 * lq;
            s16x8 fq[4];
#pragma unroll
            for (int t = 0; t < 4; ++t) {
                s16x8 tmp;
#pragma unroll
                for (int j = 0; j < 8; ++j)
                    tmp[j] = (short)f2bf(qm[((size_t)b * SB + sbase + j) * MM + t * 16 + l15]);
                fq[t] = tmp;
            }
#pragma unroll
            for (int at = 0; at < 4; ++at)
#pragma unroll
                for (int bt = 0; bt < 4; ++bt)
                    acc[at][bt] = __builtin_amdgcn_mfma_f32_16x16x32_bf16(fq[at], fq[bt],
                                                                         acc[at][bt], 0, 0, 0);
        }
#pragma unroll
        for (int at = 0; at < 4; ++at)
#pragma unroll
            for (int bt = 0; bt < 4; ++bt)
#pragma unroll
                for (int i = 0; i < 4; ++i)
                    part[w][at * 16 + lq * 4 + i][bt * 16 + l15] = acc[at][bt][i];
        __syncthreads();
        for (int e = tid * 16; e < tid * 16 + 16; ++e) {
            const int r = e >> 6, c = e & 63;
            gq[r][c] = part[0][r][c] + part[1][r][c] + part[2][r][c] + part[3][r][c];
        }
        __syncthreads();
        // phase 2: Gk + dot with Gq
#pragma unroll
        for (int i = 0; i < 4; ++i)
#pragma unroll
            for (int j = 0; j < 4; ++j) acc[i][j] = (f32x4){0.f, 0.f, 0.f, 0.f};
        for (int kt2 = 0; kt2 < 8; ++kt2) {
            const int sbase = w * 256 + kt2 * 32 + 8 * lq;
            s16x8 fk[4];
#pragma unroll
            for (int t = 0; t < 4; ++t) {
                s16x8 tmp;
#pragma unroll
                for (int j = 0; j < 8; ++j)
                    tmp[j] = (short)f2bf(kvm[((size_t)b * SB + sbase + j) * MM + t * 16 + l15]);
                fk[t] = tmp;
            }
#pragma unroll
            for (int at = 0; at < 4; ++at)
#pragma unroll
                for (int bt = 0; bt < 4; ++bt)
                    acc[at][bt] = __builtin_amdgcn_mfma_f32_16x16x32_bf16(fk[at], fk[bt],
                                                                         acc[at][bt], 0, 0, 0);
        }
#pragma unroll
        for (int at = 0; at < 4; ++at)
#pragma unroll
            for (int bt = 0; bt < 4; ++bt)
#pragma unroll
                for (int i = 0; i < 4; ++i)
                    part[w][at * 16 + lq * 4 + i][bt * 16 + l15] = acc[at][bt][i];
        __syncthreads();
        float ss = 0.f;
        for (int e = tid * 16; e < tid * 16 + 16; ++e) {
            const int r = e >> 6, c = e & 63;
            const float gk = part[0][r][c] + part[1][r][c] + part[2][r][c] + part[3][r][c];
            ss += gk * gq[r][c];
        }
#pragma unroll
        for (int mk = 1; mk < 64; mk <<= 1) ss += __shfl_xor(ss, mk);
        if (l == 0) red[w] = ss;
        __syncthreads();
        if (tid == 0) {
            const float S = red[0] + red[1] + red[2] + red[3];
            const float a = alpha_p[0];
            cscale[b] = a / (sqrtf(a * a * S) + 1e-5f);
        }
    }
}

// ---------------------------------------------------------------------------
// Flash attention, fixed-anchor softmax (no max tracking / rescale):
// p = exp(score/8 - 16); final O = sum(p*V)/sum(p) is anchor-invariant.
// grid 512 = 64 bh x 8 q-splits of 128 rows (XCD decode: same-bh -> same XCD).
// 8 waves x 16 q-rows, kv-tiles of 64 dbuf'd in LDS (1 K + 1 V gload/thread),
// tiles >= vl skipped. LDS 48KB -> 3 blocks/CU. Epilogue adds X = qm@U^T * cs.
// ---------------------------------------------------------------------------
__global__ __launch_bounds__(512, 6) void attn_kernel(const unsigned short* qh, const unsigned short* kh,
                                                      const unsigned short* vht, const unsigned short* U,
                                                      const float* cscale, const float* qm,
                                                      const int* valid_lens, unsigned short* aout) {
    const int wg = blockIdx.x;
    const int xcd = wg & 7, ii = wg >> 3;
    const int bh = (ii >> 3) * 8 + xcd;
    const int q0 = (ii & 7) * 128;
    const int b = bh >> 4, h = bh & 15;
    const int tid = threadIdx.x, l = tid & 63, w = tid >> 6;
    const int l15 = l & 15, lq = l >> 4;
    const int vl = valid_lens[b];
    const float cs = cscale[b];
    const int ntile = (vl + 63) >> 6;

    __shared__ unsigned short Kt[2][64][64];   // [buf][key][dh], granule^=(key&7)
    __shared__ unsigned short Vt[2][64][64];   // [buf][dh][key], granule^=(dh&7)
    __shared__ unsigned short Pl[8][16][64];   // per-wave P, col^=(8*(row&7))

    const int sr = tid >> 3;                   // staging row 0..63
    const int gs = (tid & 7) ^ (sr & 7);       // pre-swizzled source granule
    const unsigned short* khb = kh + (size_t)bh * SB * DHD;
    const unsigned short* vhb = vht + (size_t)bh * DHD * SB;

    auto STAGE = [&](int bb, int t) {
        const int kv0 = t << 6;
        gload_lds16(khb + (size_t)(kv0 + sr) * DHD + gs * 8, &Kt[bb][w * 8][0]);
        gload_lds16(vhb + (size_t)sr * SB + kv0 + gs * 8, &Vt[bb][w * 8][0]);
    };

    // Q fragments for this wave's 16 rows
    s16x8 aq[2];
#pragma unroll
    for (int kt = 0; kt < 2; ++kt)
        aq[kt] = *(const s16x8*)(qh + ((size_t)bh * SB + q0 + w * 16 + l15) * DHD + kt * 32 + 8 * lq);

    float l_[4];
    f32x4 oacc[4];
#pragma unroll
    for (int i = 0; i < 4; ++i) l_[i] = 0.f;
#pragma unroll
    for (int nd = 0; nd < 4; ++nd) oacc[nd] = (f32x4){0.f, 0.f, 0.f, 0.f};

    STAGE(0, 0);
    __syncthreads();
    int cur = 0;
    for (int t = 0; t < ntile; ++t) {
        if (t + 1 < ntile) STAGE(cur ^ 1, t + 1);
        const int kv0 = t << 6;
        const bool bdry = (kv0 + 64 > vl);

        // ---- QK^T (B-frags from swizzled Kt) ----
        f32x4 sc[4];
#pragma unroll
        for (int nt = 0; nt < 4; ++nt) {
            const int r = nt * 16 + l15;
            s16x8 b0 = *(const s16x8*)(&Kt[cur][r][((lq) ^ (r & 7)) * 8]);
            s16x8 b1 = *(const s16x8*)(&Kt[cur][r][((4 + lq) ^ (r & 7)) * 8]);
            f32x4 z = (f32x4){0.f, 0.f, 0.f, 0.f};
            z = __builtin_amdgcn_mfma_f32_16x16x32_bf16(aq[0], b0, z, 0, 0, 0);
            sc[nt] = __builtin_amdgcn_mfma_f32_16x16x32_bf16(aq[1], b1, z, 0, 0, 0);
        }

        // ---- p = exp(s/8 - 16) (fixed anchor), accumulate l, write P ----
#pragma unroll
        for (int nt = 0; nt < 4; ++nt) {
            const bool ok = !bdry || (kv0 + nt * 16 + l15 < vl);
#pragma unroll
            for (int i = 0; i < 4; ++i) {
                const float p = ok ? __expf(fmaf(sc[nt][i], 0.125f, -16.0f)) : 0.f;
                l_[i] += p;
                const int pr = lq * 4 + i;
                Pl[w][pr][(nt * 16 + l15) ^ (8 * (pr & 7))] = f2bf(p);
            }
        }

        // ---- PV accumulate ----
#pragma unroll
        for (int kt = 0; kt < 2; ++kt) {
            s16x8 pa = *(const s16x8*)(&Pl[w][l15][((kt * 4 + lq) ^ (l15 & 7)) * 8]);
#pragma unroll
            for (int nd = 0; nd < 4; ++nd) {
                const int r = nd * 16 + l15;
                s16x8 vb = *(const s16x8*)(&Vt[cur][r][((kt * 4 + lq) ^ (r & 7)) * 8]);
                oacc[nd] = __builtin_amdgcn_mfma_f32_16x16x32_bf16(pa, vb, oacc[nd], 0, 0, 0);
            }
        }
        __syncthreads();
        cur ^= 1;
    }

    // reduce lane-partial softmax denominators across the 16 lanes of each row
#pragma unroll
    for (int mk = 1; mk < 16; mk <<= 1)
#pragma unroll
        for (int i = 0; i < 4; ++i) l_[i] += __shfl_xor(l_[i], mk);

    // ---- epilogue: X = qm @ U^T, out = O/l + X*cs ----
    s16x8 xa[2];
#pragma unroll
    for (int kt2 = 0; kt2 < 2; ++kt2) {
        const float* qp = qm + ((size_t)b * SB + q0 + w * 16 + l15) * MM + kt2 * 32 + 8 * lq;
        f32x4 qa = *(const f32x4*)qp;
        f32x4 qb2 = *(const f32x4*)(qp + 4);
        s16x8 at;
        at[0] = (short)f2bf(qa[0]);  at[1] = (short)f2bf(qa[1]);
        at[2] = (short)f2bf(qa[2]);  at[3] = (short)f2bf(qa[3]);
        at[4] = (short)f2bf(qb2[0]); at[5] = (short)f2bf(qb2[1]);
        at[6] = (short)f2bf(qb2[2]); at[7] = (short)f2bf(qb2[3]);
        xa[kt2] = at;
    }
    float rinv[4];
#pragma unroll
    for (int i = 0; i < 4; ++i) rinv[i] = 1.f / l_[i];
#pragma unroll
    for (int nd = 0; nd < 4; ++nd) {
        f32x4 xacc = (f32x4){0.f, 0.f, 0.f, 0.f};
#pragma unroll
        for (int kt2 = 0; kt2 < 2; ++kt2) {
            s16x8 bu = *(const s16x8*)(U + ((size_t)bh * 64 + nd * 16 + l15) * 64 + kt2 * 32 + 8 * lq);
            xacc = __builtin_amdgcn_mfma_f32_16x16x32_bf16(xa[kt2], bu, xacc, 0, 0, 0);
        }
#pragma unroll
        for (int i = 0; i < 4; ++i) {
            const int row = q0 + w * 16 + lq * 4 + i;
            const float val = oacc[nd][i] * rinv[i] + xacc[i] * cs;
            aout[((size_t)b * SB + row) * DD + h * DHD + nd * 16 + l15] = f2bf(val);
        }
    }
}

// ---------------------------------------------------------------------------
extern "C" void kernel_launch(void* const* d_in, const int* in_sizes, int n_in,
                              void* d_out, int out_size, void* d_ws, size_t ws_size,
                              hipStream_t stream) {
    const float* q   = (const float*)d_in[0];
    const float* k   = (const float*)d_in[1];
    const float* v   = (const float*)d_in[2];
    const float* qm  = (const float*)d_in[3];
    const float* kvm = (const float*)d_in[4];
    const int* vl    = (const int*)d_in[5];
    const float* Wq  = (const float*)d_in[6];
    const float* Wk  = (const float*)d_in[7];
    const float* Wv  = (const float*)d_in[8];
    const float* Wo  = (const float*)d_in[9];
    const float* alpha = (const float*)d_in[10];

    char* ws = (char*)d_ws;
    unsigned short* Wt  = (unsigned short*)(ws);                        // 0..8MB
    unsigned short* qb  = (unsigned short*)(ws + ((size_t)8  << 20));   // 8..16MB
    unsigned short* kb  = (unsigned short*)(ws + ((size_t)16 << 20));   // 16..24MB
    unsigned short* vb  = (unsigned short*)(ws + ((size_t)24 << 20));   // 24..32MB
    unsigned short* qhp = (unsigned short*)(ws + ((size_t)32 << 20));   // 32..40MB
    unsigned short* khp = (unsigned short*)(ws + ((size_t)40 << 20));   // 40..48MB
    unsigned short* vht = (unsigned short*)(ws + ((size_t)48 << 20));   // 48..56MB
    unsigned short* U   = (unsigned short*)(ws + ((size_t)8  << 20));   // reuse qb (dead)
    float* csc          = (float*)(ws + ((size_t)9 << 20));             // 16B
    unsigned short* aout = (unsigned short*)(ws + ((size_t)16 << 20));  // reuse kb (dead)

    cvtw_kernel<<<10240, 256, 0, stream>>>(q, k, v, qb, kb, vb, Wq, Wk, Wv, Wo, Wt);
    gemm_qkv_kernel<<<768, 512, 0, stream>>>(qb, kb, vb, Wt, qhp, khp, vht);
    ukgram_kernel<<<68, 256, 0, stream>>>(vht, qm, kvm, alpha, U, csc);
    attn_kernel<<<512, 512, 0, stream>>>(qhp, khp, vht, U, csc, qm, vl, aout);
    gemm_o_kernel<<<256, 512, 0, stream>>>(aout, Wt + 3 * (1u << 20), (float*)d_out);
}